// Round 15
// baseline (7001.106 us; speedup 1.0000x reference)
//
#include <hip/hip_runtime.h>
#include <hip/hip_fp16.h>

// LSTM autoencoder B=64,S=256,D=H=1024,L=2 — persistent kernel, round 15.
// = round 14 EXACT (passing, 6847us) with ONE isolated change: r12's packed
//   EPI stores. Each wave's h/femb output goes out as 32x 8B dwordx2 sc0 sc1
//   (quad-shuffle pack, lane c4==0 stores) instead of 128x scattered 2B
//   stores. Targets the end-of-phase store DRAIN — the one major term never
//   isolated (r12 bundled it with a 16x poll regression; its EPI refcheck'd).
// Everything else (poll16 targets, E/F prefetch, pipelines, staging, slots)
// is byte-identical to r14.

#define NBLK 256
#define NTHR 256
#define LDS_BYTES (128 * 1024)
#define HS 65536   // halfs per h slot (64*1024)

typedef _Float16 half8 __attribute__((ext_vector_type(8)));
typedef float    f32x4 __attribute__((ext_vector_type(4)));
typedef unsigned uint32x2 __attribute__((ext_vector_type(2)));

__device__ __forceinline__ float sigm_(float x) { return 1.f / (1.f + __expf(-x)); }
__device__ __forceinline__ float tanh_(float x) {
  float e = __expf(-2.f * fabsf(x));
  float r = (1.f - e) / (1.f + e);
  return x >= 0.f ? r : -r;
}

__global__ __launch_bounds__(256) void cvt_x(const float* __restrict__ src,
                                             __half* __restrict__ dst, int n) {
  int i = blockIdx.x * 256 + threadIdx.x;
  if (i < n) dst[i] = __float2half(src[i]);
}

__global__ void fail_mark(float* out, float ws_mb) { out[0] = 1.0e6f * ws_mb; }

// ---- async 8x16B load issue; outputs EARLY-CLOBBER so none alias the addr pair ----
__device__ __forceinline__ void issue8c(const __half* p,
    half8& r0, half8& r1, half8& r2, half8& r3,
    half8& r4, half8& r5, half8& r6, half8& r7) {
  asm volatile(
    "global_load_dwordx4 %0, %8, off sc0 sc1\n\t"
    "global_load_dwordx4 %1, %8, off offset:64 sc0 sc1\n\t"
    "global_load_dwordx4 %2, %8, off offset:128 sc0 sc1\n\t"
    "global_load_dwordx4 %3, %8, off offset:192 sc0 sc1\n\t"
    "global_load_dwordx4 %4, %8, off offset:256 sc0 sc1\n\t"
    "global_load_dwordx4 %5, %8, off offset:320 sc0 sc1\n\t"
    "global_load_dwordx4 %6, %8, off offset:384 sc0 sc1\n\t"
    "global_load_dwordx4 %7, %8, off offset:448 sc0 sc1"
    : "=&v"(r0), "=&v"(r1), "=&v"(r2), "=&v"(r3),
      "=&v"(r4), "=&v"(r5), "=&v"(r6), "=&v"(r7)
    : "v"(p) : "memory");
}
__device__ __forceinline__ void issue8p(const __half* p,
    half8& r0, half8& r1, half8& r2, half8& r3,
    half8& r4, half8& r5, half8& r6, half8& r7) {
  asm volatile(
    "global_load_dwordx4 %0, %8, off\n\t"
    "global_load_dwordx4 %1, %8, off offset:64\n\t"
    "global_load_dwordx4 %2, %8, off offset:128\n\t"
    "global_load_dwordx4 %3, %8, off offset:192\n\t"
    "global_load_dwordx4 %4, %8, off offset:256\n\t"
    "global_load_dwordx4 %5, %8, off offset:320\n\t"
    "global_load_dwordx4 %6, %8, off offset:384\n\t"
    "global_load_dwordx4 %7, %8, off offset:448"
    : "=&v"(r0), "=&v"(r1), "=&v"(r2), "=&v"(r3),
      "=&v"(r4), "=&v"(r5), "=&v"(r6), "=&v"(r7)
    : "v"(p) : "memory");
}

__device__ __forceinline__ void st8_coh(__half* p, uint32x2 v) {
  asm volatile("global_store_dwordx2 %0, %1, off sc0 sc1" :: "v"(p), "v"(v) : "memory");
}

// fused poll of both counter sets (set0 at c, set1 at c+4096B), one round trip
__device__ __forceinline__ void poll16(const unsigned* c, unsigned& sA, unsigned& sB) {
  unsigned a0,a1,a2,a3,a4,a5,a6,a7, b0,b1,b2,b3,b4,b5,b6,b7;
  const unsigned* c2 = c + 1024;
  asm volatile(
    "global_load_dword %0, %16, off sc0 sc1\n\t"
    "global_load_dword %1, %16, off offset:64 sc0 sc1\n\t"
    "global_load_dword %2, %16, off offset:128 sc0 sc1\n\t"
    "global_load_dword %3, %16, off offset:192 sc0 sc1\n\t"
    "global_load_dword %4, %16, off offset:256 sc0 sc1\n\t"
    "global_load_dword %5, %16, off offset:320 sc0 sc1\n\t"
    "global_load_dword %6, %16, off offset:384 sc0 sc1\n\t"
    "global_load_dword %7, %16, off offset:448 sc0 sc1\n\t"
    "global_load_dword %8, %17, off sc0 sc1\n\t"
    "global_load_dword %9, %17, off offset:64 sc0 sc1\n\t"
    "global_load_dword %10, %17, off offset:128 sc0 sc1\n\t"
    "global_load_dword %11, %17, off offset:192 sc0 sc1\n\t"
    "global_load_dword %12, %17, off offset:256 sc0 sc1\n\t"
    "global_load_dword %13, %17, off offset:320 sc0 sc1\n\t"
    "global_load_dword %14, %17, off offset:384 sc0 sc1\n\t"
    "global_load_dword %15, %17, off offset:448 sc0 sc1\n\t"
    "s_waitcnt vmcnt(0)"
    : "=&v"(a0), "=&v"(a1), "=&v"(a2), "=&v"(a3),
      "=&v"(a4), "=&v"(a5), "=&v"(a6), "=&v"(a7),
      "=&v"(b0), "=&v"(b1), "=&v"(b2), "=&v"(b3),
      "=&v"(b4), "=&v"(b5), "=&v"(b6), "=&v"(b7)
    : "v"(c), "v"(c2) : "memory");
  sA = a0 + a1 + a2 + a3 + a4 + a5 + a6 + a7;
  sB = b0 + b1 + b2 + b3 + b4 + b5 + b6 + b7;
}

#define WAITVM(n) do { asm volatile("s_waitcnt vmcnt(" #n ")" ::: "memory"); \
                       __builtin_amdgcn_sched_barrier(0); } while (0)
#define DRAIN()   asm volatile("s_waitcnt vmcnt(0)" ::: "memory")
#define BANK(X) X##0, X##1, X##2, X##3, X##4, X##5, X##6, X##7
// chunks 0-3: s0 (plain); chunks 4-7: s1 — COHERENT when coh1 (l1's h1pp ping-pong)
#define ISSUE(X, c) do { const __half* _p = ((c) < 4 ? pa + (c) * 256 : pb + ((c) - 4) * 256); \
                         if (((c) >= 4) && coh1) issue8c(_p, BANK(X)); \
                         else issue8p(_p, BANK(X)); } while (0)
// 16 MFMAs per chunk: two independent acc chains (n=0 cols 0-15, n=1 cols 16-31)
#define MFMA16(X, c) do { const __half* _b = ldsb + (c) * 8192; \
  accA = __builtin_amdgcn_mfma_f32_16x16x32_f16(X##0, *(const half8*)(_b + 0*1024), accA, 0,0,0); \
  accB = __builtin_amdgcn_mfma_f32_16x16x32_f16(X##0, *(const half8*)(_b + 0*1024 + 128), accB, 0,0,0); \
  accA = __builtin_amdgcn_mfma_f32_16x16x32_f16(X##1, *(const half8*)(_b + 1*1024), accA, 0,0,0); \
  accB = __builtin_amdgcn_mfma_f32_16x16x32_f16(X##1, *(const half8*)(_b + 1*1024 + 128), accB, 0,0,0); \
  accA = __builtin_amdgcn_mfma_f32_16x16x32_f16(X##2, *(const half8*)(_b + 2*1024), accA, 0,0,0); \
  accB = __builtin_amdgcn_mfma_f32_16x16x32_f16(X##2, *(const half8*)(_b + 2*1024 + 128), accB, 0,0,0); \
  accA = __builtin_amdgcn_mfma_f32_16x16x32_f16(X##3, *(const half8*)(_b + 3*1024), accA, 0,0,0); \
  accB = __builtin_amdgcn_mfma_f32_16x16x32_f16(X##3, *(const half8*)(_b + 3*1024 + 128), accB, 0,0,0); \
  accA = __builtin_amdgcn_mfma_f32_16x16x32_f16(X##4, *(const half8*)(_b + 4*1024), accA, 0,0,0); \
  accB = __builtin_amdgcn_mfma_f32_16x16x32_f16(X##4, *(const half8*)(_b + 4*1024 + 128), accB, 0,0,0); \
  accA = __builtin_amdgcn_mfma_f32_16x16x32_f16(X##5, *(const half8*)(_b + 5*1024), accA, 0,0,0); \
  accB = __builtin_amdgcn_mfma_f32_16x16x32_f16(X##5, *(const half8*)(_b + 5*1024 + 128), accB, 0,0,0); \
  accA = __builtin_amdgcn_mfma_f32_16x16x32_f16(X##6, *(const half8*)(_b + 6*1024), accA, 0,0,0); \
  accB = __builtin_amdgcn_mfma_f32_16x16x32_f16(X##6, *(const half8*)(_b + 6*1024 + 128), accB, 0,0,0); \
  accA = __builtin_amdgcn_mfma_f32_16x16x32_f16(X##7, *(const half8*)(_b + 7*1024), accA, 0,0,0); \
  accB = __builtin_amdgcn_mfma_f32_16x16x32_f16(X##7, *(const half8*)(_b + 7*1024 + 128), accB, 0,0,0); \
  } while (0)

// r11's exact 4-bank pipeline
#define PIPE_GENERIC() do { \
  ISSUE(A, 0); ISSUE(B, 1); ISSUE(C, 2); ISSUE(D, 3); \
  WAITVM(24); MFMA16(A, 0); ISSUE(A, 4); \
  WAITVM(24); MFMA16(B, 1); ISSUE(B, 5); \
  WAITVM(24); MFMA16(C, 2); ISSUE(C, 6); \
  WAITVM(24); MFMA16(D, 3); ISSUE(D, 7); \
  WAITVM(24); MFMA16(A, 4); \
  WAITVM(16); MFMA16(B, 5); \
  WAITVM(8);  MFMA16(C, 6); \
  WAITVM(0);  MFMA16(D, 7); \
} while (0)

// chunks 0,1 already RESIDENT in E,F (prefetched last iter BEFORE the drain)
#define PIPE_PF() do { \
  ISSUE(A, 2); ISSUE(B, 3); ISSUE(C, 4); ISSUE(D, 5); \
  MFMA16(E, 0); MFMA16(F, 1); \
  WAITVM(24); MFMA16(A, 2); ISSUE(A, 6); \
  WAITVM(24); MFMA16(B, 3); ISSUE(B, 7); \
  WAITVM(16); MFMA16(C, 4); \
  WAITVM(8);  MFMA16(D, 5); \
  WAITVM(8);  MFMA16(A, 6); \
  WAITVM(0);  MFMA16(B, 7); \
} while (0)

#define PREFETCH_EF(ptr) do { issue8p((ptr), BANK(E)); issue8p((ptr) + 256, BANK(F)); } while (0)

// LSTM cell epilogue, r12's packed-store version (refcheck'd in r12):
// all 4 gi-groups compute identical h per (b, j-quad); quad-shuffle packs
// j=J0..J0+3 into one dwordx2; lane c4==0 stores 8B sc0 sc1 (h and femb-rev).
#define EPI(ACC, CST, BB, NIDX) do { \
  const int J0 = jb * 8 + (NIDX) * 4; \
  _Pragma("unroll") \
  for (int r = 0; r < 4; ++r) { \
    float v = ACC[r] + (BB); \
    float vx4  = __shfl_xor(v, 4); \
    float vx8  = __shfl_xor(v, 8); \
    float vx12 = __shfl_xor(vx4, 8); \
    float vi = gi == 0 ? v    : gi == 1 ? vx4  : gi == 2 ? vx8  : vx12; \
    float vf = gi == 0 ? vx4  : gi == 1 ? v    : gi == 2 ? vx12 : vx8; \
    float vg = gi == 0 ? vx8  : gi == 1 ? vx12 : gi == 2 ? v    : vx4; \
    float vo = gi == 0 ? vx12 : gi == 1 ? vx8  : gi == 2 ? vx4  : v; \
    float cn = sigm_(vf) * CST[r] + sigm_(vi) * tanh_(vg); \
    CST[r] = cn; \
    float h = sigm_(vo) * tanh_(cn); \
    const int b = mtile * 16 + kq * 4 + r; \
    int hu = (int)__half_as_ushort(__float2half(h)); \
    int qb = lane & ~3; \
    int v0 = __shfl(hu, qb), v1 = __shfl(hu, qb + 1); \
    int v2 = __shfl(hu, qb + 2), v3 = __shfl(hu, qb + 3); \
    if (c4 == 0) { \
      uint32x2 pk = { (unsigned)(v0 & 0xffff) | ((unsigned)v1 << 16), \
                      (unsigned)(v2 & 0xffff) | ((unsigned)v3 << 16) }; \
      st8_coh(hdst + (size_t)b * 1024 + J0, pk); \
    } \
    if (layer == 1) { \
      if (seg == 0) { \
        if (p == 256) { \
          if (gi == 0) out[(size_t)b * 1024 + J0 + (lane & 3)] = h; \
          if (c4 == 0) { \
            uint32x2 pr = { (unsigned)(v3 & 0xffff) | ((unsigned)v2 << 16), \
                            (unsigned)(v1 & 0xffff) | ((unsigned)v0 << 16) }; \
            st8_coh(femb + (size_t)b * 1024 + (1020 - J0), pr); \
          } \
        } \
      } else { \
        if (gi == 0) out[65536 + ((size_t)b * 256 + (p - 1)) * 1024 + (1023 - (J0 + (lane & 3)))] = h; \
      } \
    } \
  } } while (0)

__global__ __launch_bounds__(256, 1) void lstm_persist(
    const __half* __restrict__ xf16,
    const float* __restrict__ eWih0, const float* __restrict__ eWhh0,
    const float* __restrict__ eWih1, const float* __restrict__ eWhh1,
    const float* __restrict__ dWih0, const float* __restrict__ dWhh0,
    const float* __restrict__ dWih1, const float* __restrict__ dWhh1,
    const float* __restrict__ ebi0, const float* __restrict__ ebh0,
    const float* __restrict__ ebi1, const float* __restrict__ ebh1,
    const float* __restrict__ dbi0, const float* __restrict__ dbh0,
    const float* __restrict__ dbi1, const float* __restrict__ dbh1,
    __half* __restrict__ hE0,   // 257 fresh slots (encoder h0)
    __half* __restrict__ hD0,   // 257 fresh slots (decoder h0)
    __half* __restrict__ h1pp,  // 2-slot ping-pong (h1, both segments)
    __half* __restrict__ femb, float* __restrict__ out,
    unsigned* __restrict__ ctr) {
  extern __shared__ __half lds[];
  const int tid   = threadIdx.x, lane = tid & 63;
  const int mtile = tid >> 6;          // wave id = m-tile (batch rows mtile*16..+16)
  const int layer = blockIdx.x >> 7;
  const int jb    = blockIdx.x & 127;
  const int c4 = lane & 15, kq = lane >> 4;
  const int gi = c4 >> 2;
  const int arow = mtile * 16 + c4;
  unsigned* myarr = ctr + (layer ? 1024 : 0) + (blockIdx.x & 7) * 16;  // own set
  const int coh1 = (layer == 1);       // s1 coherent only for l1's h1pp (r11-exact)

  f32x4 cA = {0.f, 0.f, 0.f, 0.f};     // cell state (n=0 tile), regs enc->dec
  f32x4 cB = {0.f, 0.f, 0.f, 0.f};     // cell state (n=1 tile)

  for (int seg = 0; seg < 2; ++seg) {
    // ---- stage [32 cols x 2048 K] f16 weights into LDS (r11 exact) ----
    const float* Wih; const float* Whh; int flip = 0;
    if (seg == 0) { Wih = layer ? eWih1 : eWih0; Whh = layer ? eWhh1 : eWhh0; }
    else { Wih = layer ? dWih1 : dWih0; Whh = layer ? dWhh1 : dWhh0; flip = (layer == 0); }
    const int k0 = tid * 8;
    for (int i = 0; i < 32; ++i) {
      int cc4 = i & 15, ct = i >> 4;
      int n = (cc4 >> 2) * 1024 + jb * 8 + ct * 4 + (cc4 & 3);
      half8 t;
      if (k0 < 1024) {
        if (flip) {
          #pragma unroll
          for (int e = 0; e < 8; ++e) t[e] = (_Float16)Wih[(size_t)n * 1024 + 1023 - k0 - e];
        } else {
          #pragma unroll
          for (int e = 0; e < 8; ++e) t[e] = (_Float16)Wih[(size_t)n * 1024 + k0 + e];
        }
      } else {
        #pragma unroll
        for (int e = 0; e < 8; ++e) t[e] = (_Float16)Whh[(size_t)n * 1024 + k0 - 1024 + e];
      }
      *(half8*)(lds + ((size_t)tid * 32 + i) * 8) = t;
    }
    const float* bi = (seg == 0) ? (layer ? ebi1 : ebi0) : (layer ? dbi1 : dbi0);
    const float* bh = (seg == 0) ? (layer ? ebh1 : ebh0) : (layer ? dbh1 : dbh0);
    const int nl0 = gi * 1024 + jb * 8 + (lane & 3);
    const float bb0 = bi[nl0] + bh[nl0];
    const float bb1 = bi[nl0 + 4] + bh[nl0 + 4];
    __syncthreads();
    DRAIN();  // clean vmcnt before counted phases

    const __half* ldsb = lds + ((size_t)kq * 32 + c4) * 8;
    __half* h0b = seg ? hD0 : hE0;

    half8 A0,A1,A2,A3,A4,A5,A6,A7, B0,B1,B2,B3,B4,B5,B6,B7,
          C0,C1,C2,C3,C4,C5,C6,C7, D0,D1,D2,D3,D4,D5,D6,D7,
          E0,E1,E2,E3,E4,E5,E6,E7, F0,F1,F2,F3,F4,F5,F6,F7;
    int havepf = 0;

    for (int p = 0; p <= 256; ++p) {
      // ---- start-of-iter wait (decoupled targets, r14 exact) ----
      const unsigned T  = (unsigned)(seg * 257 + p) * 128u;
      const unsigned tA = (layer == 1) ? T + 128u : T;                // set0 (l0)
      const unsigned tB = (layer == 1) ? T
                         : ((seg == 1 && p == 0) ? 257u * 128u : 0u); // set1 (l1/femb)
      if (tid == 0 && (tA | tB)) {
        unsigned sA, sB;
        int g = 0;
        for (;;) {
          poll16(ctr, sA, sB);
          if (sA >= tA && sB >= tB) break;
          __builtin_amdgcn_s_sleep(1);
          if (++g > (1 << 18)) break;   // hang safety: break (wrong results, no hang)
        }
      }
      __syncthreads();

      const int active = (layer == 0) ? (p <= 255) : (p >= 1);
      if (active) {
        // source selection (r11 exact)
        const __half* l0rec = (seg && p == 0) ? hE0 + (size_t)256 * HS
                                              : h0b + (size_t)p * HS;
        const __half* l1in  = h0b + (size_t)p * HS;
        const __half* l1rec = h1pp + (size_t)((p + 1) & 1) * HS;
        const __half* s1 = (layer == 0) ? l0rec : l1rec;
        const __half* s0;
        long long st0;
        if (layer == 0) {
          if (seg == 0)      { s0 = xf16 + (size_t)p * 1024;       st0 = 262144; }
          else if (p == 0)   { s0 = femb;                          st0 = 1024;   }
          else               { s0 = xf16 + (size_t)(p - 1) * 1024; st0 = 262144; }
        } else             { s0 = l1in;                            st0 = 1024;   }

        const __half* pa = s0 + (long long)arow * st0 + kq * 8;
        const __half* pb = s1 + (long long)arow * 1024 + kq * 8;
        f32x4 accA = {0.f, 0.f, 0.f, 0.f};
        f32x4 accB = {0.f, 0.f, 0.f, 0.f};
        if (havepf) PIPE_PF(); else PIPE_GENERIC();

        __half* hdst = (layer == 0) ? h0b + (size_t)(p + 1) * HS
                                    : h1pp + (size_t)(p & 1) * HS;
        EPI(accA, cA, bb0, 0);
        EPI(accB, cB, bb1, 1);
      }

      // ---- prefetch next iter's s0 chunks 0,1 (r14 exact: BEFORE the drain) ----
      havepf = 0;
      if (p < 256) {
        const int np = p + 1;
        const int nactive = (layer == 0) ? (np <= 255) : 1;   // l1: np>=1 always
        if (nactive) {
          const __half* ns0;
          long long nst;
          if (layer == 0) {  // x is static read-only (seg1: s0(np)=x[np-1])
            ns0 = (seg == 0) ? xf16 + (size_t)np * 1024
                             : xf16 + (size_t)(np - 1) * 1024;
            nst = 262144;
          } else {           // h0(np): this iter's poll ensured l0 set >= T+128
            ns0 = h0b + (size_t)np * HS;
            nst = 1024;
          }
          const __half* npa = ns0 + (long long)arow * nst + kq * 8;
          PREFETCH_EF(npa);
          havepf = 1;
        }
      }

      // ---- end-of-iter: drain stores+prefetch, arrive on own set ----
      DRAIN();
      __syncthreads();
      if (tid == 0)
        __hip_atomic_fetch_add(myarr, 1u, __ATOMIC_RELAXED, __HIP_MEMORY_SCOPE_AGENT);
    }
    __syncthreads();   // quiesce before next seg's LDS restage
  }
}

extern "C" void kernel_launch(void* const* d_in, const int* in_sizes, int n_in,
                              void* d_out, int out_size, void* d_ws, size_t ws_size,
                              hipStream_t stream) {
  const float* x     = (const float*)d_in[0];
  const float* eWih0 = (const float*)d_in[1];
  const float* eWhh0 = (const float*)d_in[2];
  const float* ebih0 = (const float*)d_in[3];
  const float* ebhh0 = (const float*)d_in[4];
  const float* eWih1 = (const float*)d_in[5];
  const float* eWhh1 = (const float*)d_in[6];
  const float* ebih1 = (const float*)d_in[7];
  const float* ebhh1 = (const float*)d_in[8];
  const float* dWih0 = (const float*)d_in[9];
  const float* dWhh0 = (const float*)d_in[10];
  const float* dbih0 = (const float*)d_in[11];
  const float* dbhh0 = (const float*)d_in[12];
  const float* dWih1 = (const float*)d_in[13];
  const float* dWhh1 = (const float*)d_in[14];
  const float* dbih1 = (const float*)d_in[15];
  const float* dbhh1 = (const float*)d_in[16];
  float* out = (float*)d_out;

  char* ws = (char*)d_ws;
  size_t off = 0;
  auto alloc = [&](size_t bytes) { char* p = ws + off; off += (bytes + 255) & ~(size_t)255; return p; };
  const size_t SLOT = (size_t)HS * sizeof(__half);            // 128KB
  __half* xf16 = (__half*)alloc((size_t)64 * 256 * 1024 * sizeof(__half));  // 32MB
  __half* hE0  = (__half*)alloc(257 * SLOT);                  // 32.1MB fresh slots
  __half* hD0  = (__half*)alloc(257 * SLOT);                  // 32.1MB fresh slots
  __half* h1pp = (__half*)alloc(2 * SLOT);                    // h1 ping-pong (coherent)
  __half* femb = (__half*)alloc(SLOT);
  unsigned* ctr = (unsigned*)alloc(8192);

  if (ws_size < off) {  // loud failure: absmax == ws_size in MB * 1e6
    hipLaunchKernelGGL(fail_mark, dim3(1), dim3(1), 0, stream,
                       out, (float)(ws_size >> 20));
    return;
  }

  const int xn = 64 * 256 * 1024;
  cvt_x<<<(xn + 255) / 256, 256, 0, stream>>>(x, xf16, xn);

  hipMemsetAsync(hE0, 0, SLOT, stream);   // h0 slot0 = zeros
  hipMemsetAsync(h1pp, 0, SLOT, stream);  // h1 slot0 = zeros
  hipMemsetAsync(ctr, 0, 8192, stream);

  hipFuncSetAttribute((const void*)lstm_persist,
                      hipFuncAttributeMaxDynamicSharedMemorySize, LDS_BYTES);
  lstm_persist<<<NBLK, NTHR, LDS_BYTES, stream>>>(
      xf16,
      eWih0, eWhh0, eWih1, eWhh1, dWih0, dWhh0, dWih1, dWhh1,
      ebih0, ebhh0, ebih1, ebhh1, dbih0, dbhh0, dbih1, dbhh1,
      hE0, hD0, h1pp, femb, out, ctr);
}

// Round 16
// 6708.764 us; speedup vs baseline: 1.0436x; 1.0436x over previous
//
#include <hip/hip_runtime.h>
#include <hip/hip_fp16.h>

// LSTM autoencoder B=64,S=256,D=H=1024,L=2 — persistent kernel, FINAL (= round 11).
// Best measured configuration: 6787us. r12-r15 isolation experiments (wave-parallel
// poll, packed stores, h0-prefetch, h1-fresh) were all null or negative and are
// reverted. Structure:
//  * 256 blocks (1/CU), 4 waves; block = (layer, 8-col j-strip); [32x2048] f16
//    weight slice in 128KB LDS (decoder l0 slice col-flipped at stage time).
//  * 2 segments (enc/dec) x 257 pipelined phases; layer-decoupled barrier sets
//    (l0 free-runs on fresh h0 slots; l1 waits l0-set >= T+128 and own set >= T).
//  * h0: 257 fresh 128KB slots/segment (plain reads, L2-absorbable; never-reused
//    addresses make staleness impossible). h1: 2-slot ping-pong, COHERENT
//    (sc0 sc1) reads — reused addresses; write-through does not invalidate a
//    reader XCD's cached line (r10's NaN proved it).
//  * All h/femb stores sc0 sc1 write-through; drained (vmcnt(0)) before arrive.
//  * 4-bank x 8-chunk counted-vmcnt load pipeline; l0 prefetches next-iter x
//    chunks into E,F before the drain.
// Converged floor: ~13.2us/phase x 514 phases — cross-XCD visibility round trip
// + max-of-256-blocks straggle + IC h-broadcast + EPI; each lever individually
// isolated null/negative in r12-r15.

#define NBLK 256
#define NTHR 256
#define LDS_BYTES (128 * 1024)
#define HS 65536   // halfs per h slot (64*1024)

typedef _Float16 half8 __attribute__((ext_vector_type(8)));
typedef float    f32x4 __attribute__((ext_vector_type(4)));

__device__ __forceinline__ float sigm_(float x) { return 1.f / (1.f + __expf(-x)); }
__device__ __forceinline__ float tanh_(float x) {
  float e = __expf(-2.f * fabsf(x));
  float r = (1.f - e) / (1.f + e);
  return x >= 0.f ? r : -r;
}

__global__ __launch_bounds__(256) void cvt_x(const float* __restrict__ src,
                                             __half* __restrict__ dst, int n) {
  int i = blockIdx.x * 256 + threadIdx.x;
  if (i < n) dst[i] = __float2half(src[i]);
}

__global__ void fail_mark(float* out, float ws_mb) { out[0] = 1.0e6f * ws_mb; }

// ---- async 8x16B load issue; outputs EARLY-CLOBBER so none alias the addr pair ----
__device__ __forceinline__ void issue8c(const __half* p,
    half8& r0, half8& r1, half8& r2, half8& r3,
    half8& r4, half8& r5, half8& r6, half8& r7) {
  asm volatile(
    "global_load_dwordx4 %0, %8, off sc0 sc1\n\t"
    "global_load_dwordx4 %1, %8, off offset:64 sc0 sc1\n\t"
    "global_load_dwordx4 %2, %8, off offset:128 sc0 sc1\n\t"
    "global_load_dwordx4 %3, %8, off offset:192 sc0 sc1\n\t"
    "global_load_dwordx4 %4, %8, off offset:256 sc0 sc1\n\t"
    "global_load_dwordx4 %5, %8, off offset:320 sc0 sc1\n\t"
    "global_load_dwordx4 %6, %8, off offset:384 sc0 sc1\n\t"
    "global_load_dwordx4 %7, %8, off offset:448 sc0 sc1"
    : "=&v"(r0), "=&v"(r1), "=&v"(r2), "=&v"(r3),
      "=&v"(r4), "=&v"(r5), "=&v"(r6), "=&v"(r7)
    : "v"(p) : "memory");
}
__device__ __forceinline__ void issue8p(const __half* p,
    half8& r0, half8& r1, half8& r2, half8& r3,
    half8& r4, half8& r5, half8& r6, half8& r7) {
  asm volatile(
    "global_load_dwordx4 %0, %8, off\n\t"
    "global_load_dwordx4 %1, %8, off offset:64\n\t"
    "global_load_dwordx4 %2, %8, off offset:128\n\t"
    "global_load_dwordx4 %3, %8, off offset:192\n\t"
    "global_load_dwordx4 %4, %8, off offset:256\n\t"
    "global_load_dwordx4 %5, %8, off offset:320\n\t"
    "global_load_dwordx4 %6, %8, off offset:384\n\t"
    "global_load_dwordx4 %7, %8, off offset:448"
    : "=&v"(r0), "=&v"(r1), "=&v"(r2), "=&v"(r3),
      "=&v"(r4), "=&v"(r5), "=&v"(r6), "=&v"(r7)
    : "v"(p) : "memory");
}

__device__ __forceinline__ void st2_coh(__half* p, float h) {
  unsigned v = (unsigned)__half_as_ushort(__float2half(h));
  asm volatile("global_store_short %0, %1, off sc0 sc1" :: "v"(p), "v"(v) : "memory");
}

// fused poll of both counter sets (set0 at c, set1 at c+4096B), one round trip
__device__ __forceinline__ void poll16(const unsigned* c, unsigned& sA, unsigned& sB) {
  unsigned a0,a1,a2,a3,a4,a5,a6,a7, b0,b1,b2,b3,b4,b5,b6,b7;
  const unsigned* c2 = c + 1024;
  asm volatile(
    "global_load_dword %0, %16, off sc0 sc1\n\t"
    "global_load_dword %1, %16, off offset:64 sc0 sc1\n\t"
    "global_load_dword %2, %16, off offset:128 sc0 sc1\n\t"
    "global_load_dword %3, %16, off offset:192 sc0 sc1\n\t"
    "global_load_dword %4, %16, off offset:256 sc0 sc1\n\t"
    "global_load_dword %5, %16, off offset:320 sc0 sc1\n\t"
    "global_load_dword %6, %16, off offset:384 sc0 sc1\n\t"
    "global_load_dword %7, %16, off offset:448 sc0 sc1\n\t"
    "global_load_dword %8, %17, off sc0 sc1\n\t"
    "global_load_dword %9, %17, off offset:64 sc0 sc1\n\t"
    "global_load_dword %10, %17, off offset:128 sc0 sc1\n\t"
    "global_load_dword %11, %17, off offset:192 sc0 sc1\n\t"
    "global_load_dword %12, %17, off offset:256 sc0 sc1\n\t"
    "global_load_dword %13, %17, off offset:320 sc0 sc1\n\t"
    "global_load_dword %14, %17, off offset:384 sc0 sc1\n\t"
    "global_load_dword %15, %17, off offset:448 sc0 sc1\n\t"
    "s_waitcnt vmcnt(0)"
    : "=&v"(a0), "=&v"(a1), "=&v"(a2), "=&v"(a3),
      "=&v"(a4), "=&v"(a5), "=&v"(a6), "=&v"(a7),
      "=&v"(b0), "=&v"(b1), "=&v"(b2), "=&v"(b3),
      "=&v"(b4), "=&v"(b5), "=&v"(b6), "=&v"(b7)
    : "v"(c), "v"(c2) : "memory");
  sA = a0 + a1 + a2 + a3 + a4 + a5 + a6 + a7;
  sB = b0 + b1 + b2 + b3 + b4 + b5 + b6 + b7;
}

#define WAITVM(n) do { asm volatile("s_waitcnt vmcnt(" #n ")" ::: "memory"); \
                       __builtin_amdgcn_sched_barrier(0); } while (0)
#define DRAIN()   asm volatile("s_waitcnt vmcnt(0)" ::: "memory")
#define BANK(X) X##0, X##1, X##2, X##3, X##4, X##5, X##6, X##7
// chunks 0-3: s0 (plain); chunks 4-7: s1 — COHERENT when coh1 (l1's h1pp ping-pong)
#define ISSUE(X, c) do { const __half* _p = ((c) < 4 ? pa + (c) * 256 : pb + ((c) - 4) * 256); \
                         if (((c) >= 4) && coh1) issue8c(_p, BANK(X)); \
                         else issue8p(_p, BANK(X)); } while (0)
// 16 MFMAs per chunk: two independent acc chains (n=0 cols 0-15, n=1 cols 16-31)
#define MFMA16(X, c) do { const __half* _b = ldsb + (c) * 8192; \
  accA = __builtin_amdgcn_mfma_f32_16x16x32_f16(X##0, *(const half8*)(_b + 0*1024), accA, 0,0,0); \
  accB = __builtin_amdgcn_mfma_f32_16x16x32_f16(X##0, *(const half8*)(_b + 0*1024 + 128), accB, 0,0,0); \
  accA = __builtin_amdgcn_mfma_f32_16x16x32_f16(X##1, *(const half8*)(_b + 1*1024), accA, 0,0,0); \
  accB = __builtin_amdgcn_mfma_f32_16x16x32_f16(X##1, *(const half8*)(_b + 1*1024 + 128), accB, 0,0,0); \
  accA = __builtin_amdgcn_mfma_f32_16x16x32_f16(X##2, *(const half8*)(_b + 2*1024), accA, 0,0,0); \
  accB = __builtin_amdgcn_mfma_f32_16x16x32_f16(X##2, *(const half8*)(_b + 2*1024 + 128), accB, 0,0,0); \
  accA = __builtin_amdgcn_mfma_f32_16x16x32_f16(X##3, *(const half8*)(_b + 3*1024), accA, 0,0,0); \
  accB = __builtin_amdgcn_mfma_f32_16x16x32_f16(X##3, *(const half8*)(_b + 3*1024 + 128), accB, 0,0,0); \
  accA = __builtin_amdgcn_mfma_f32_16x16x32_f16(X##4, *(const half8*)(_b + 4*1024), accA, 0,0,0); \
  accB = __builtin_amdgcn_mfma_f32_16x16x32_f16(X##4, *(const half8*)(_b + 4*1024 + 128), accB, 0,0,0); \
  accA = __builtin_amdgcn_mfma_f32_16x16x32_f16(X##5, *(const half8*)(_b + 5*1024), accA, 0,0,0); \
  accB = __builtin_amdgcn_mfma_f32_16x16x32_f16(X##5, *(const half8*)(_b + 5*1024 + 128), accB, 0,0,0); \
  accA = __builtin_amdgcn_mfma_f32_16x16x32_f16(X##6, *(const half8*)(_b + 6*1024), accA, 0,0,0); \
  accB = __builtin_amdgcn_mfma_f32_16x16x32_f16(X##6, *(const half8*)(_b + 6*1024 + 128), accB, 0,0,0); \
  accA = __builtin_amdgcn_mfma_f32_16x16x32_f16(X##7, *(const half8*)(_b + 7*1024), accA, 0,0,0); \
  accB = __builtin_amdgcn_mfma_f32_16x16x32_f16(X##7, *(const half8*)(_b + 7*1024 + 128), accB, 0,0,0); \
  } while (0)

// 4-bank pipeline
#define PIPE_GENERIC() do { \
  ISSUE(A, 0); ISSUE(B, 1); ISSUE(C, 2); ISSUE(D, 3); \
  WAITVM(24); MFMA16(A, 0); ISSUE(A, 4); \
  WAITVM(24); MFMA16(B, 1); ISSUE(B, 5); \
  WAITVM(24); MFMA16(C, 2); ISSUE(C, 6); \
  WAITVM(24); MFMA16(D, 3); ISSUE(D, 7); \
  WAITVM(24); MFMA16(A, 4); \
  WAITVM(16); MFMA16(B, 5); \
  WAITVM(8);  MFMA16(C, 6); \
  WAITVM(0);  MFMA16(D, 7); \
} while (0)

// chunks 0,1 already RESIDENT in E,F (prefetched last iter BEFORE the drain)
#define PIPE_PF() do { \
  ISSUE(A, 2); ISSUE(B, 3); ISSUE(C, 4); ISSUE(D, 5); \
  MFMA16(E, 0); MFMA16(F, 1); \
  WAITVM(24); MFMA16(A, 2); ISSUE(A, 6); \
  WAITVM(24); MFMA16(B, 3); ISSUE(B, 7); \
  WAITVM(16); MFMA16(C, 4); \
  WAITVM(8);  MFMA16(D, 5); \
  WAITVM(8);  MFMA16(A, 6); \
  WAITVM(0);  MFMA16(B, 7); \
} while (0)

#define PREFETCH_EF(ptr) do { issue8p((ptr), BANK(E)); issue8p((ptr) + 256, BANK(F)); } while (0)

// LSTM cell epilogue for one n-tile (gate allgather via xor-4/8 in the 16-col group)
#define EPI(ACC, CST, BB, NIDX) do { \
  _Pragma("unroll") \
  for (int r = 0; r < 4; ++r) { \
    float v = ACC[r] + (BB); \
    float vx4  = __shfl_xor(v, 4); \
    float vx8  = __shfl_xor(v, 8); \
    float vx12 = __shfl_xor(vx4, 8); \
    float vi = gi == 0 ? v    : gi == 1 ? vx4  : gi == 2 ? vx8  : vx12; \
    float vf = gi == 0 ? vx4  : gi == 1 ? v    : gi == 2 ? vx12 : vx8; \
    float vg = gi == 0 ? vx8  : gi == 1 ? vx12 : gi == 2 ? v    : vx4; \
    float vo = gi == 0 ? vx12 : gi == 1 ? vx8  : gi == 2 ? vx4  : v; \
    float cn = sigm_(vf) * CST[r] + sigm_(vi) * tanh_(vg); \
    CST[r] = cn; \
    float h = sigm_(vo) * tanh_(cn); \
    if (gi == 0) { \
      const int b = mtile * 16 + kq * 4 + r; \
      const int j = jb * 8 + (NIDX) * 4 + (lane & 3); \
      st2_coh(hdst + (size_t)b * 1024 + j, h); \
      if (layer == 1) { \
        if (seg == 0) { if (p == 256) { \
            out[(size_t)b * 1024 + j] = h; \
            st2_coh(femb + (size_t)b * 1024 + (1023 - j), h); } \
        } else { \
          out[65536 + ((size_t)b * 256 + (p - 1)) * 1024 + (1023 - j)] = h; } \
      } \
    } \
  } } while (0)

__global__ __launch_bounds__(256, 1) void lstm_persist(
    const __half* __restrict__ xf16,
    const float* __restrict__ eWih0, const float* __restrict__ eWhh0,
    const float* __restrict__ eWih1, const float* __restrict__ eWhh1,
    const float* __restrict__ dWih0, const float* __restrict__ dWhh0,
    const float* __restrict__ dWih1, const float* __restrict__ dWhh1,
    const float* __restrict__ ebi0, const float* __restrict__ ebh0,
    const float* __restrict__ ebi1, const float* __restrict__ ebh1,
    const float* __restrict__ dbi0, const float* __restrict__ dbh0,
    const float* __restrict__ dbi1, const float* __restrict__ dbh1,
    __half* __restrict__ hE0,   // 257 fresh slots (encoder h0)
    __half* __restrict__ hD0,   // 257 fresh slots (decoder h0)
    __half* __restrict__ h1pp,  // 2-slot ping-pong (h1, both segments)
    __half* __restrict__ femb, float* __restrict__ out,
    unsigned* __restrict__ ctr) {
  extern __shared__ __half lds[];
  const int tid   = threadIdx.x, lane = tid & 63;
  const int mtile = tid >> 6;          // wave id = m-tile (batch rows mtile*16..+16)
  const int layer = blockIdx.x >> 7;
  const int jb    = blockIdx.x & 127;
  const int c4 = lane & 15, kq = lane >> 4;
  const int gi = c4 >> 2;
  const int arow = mtile * 16 + c4;
  unsigned* myarr = ctr + (layer ? 1024 : 0) + (blockIdx.x & 7) * 16;  // own set
  const int coh1 = (layer == 1);       // s1 coherent only for l1's h1pp

  f32x4 cA = {0.f, 0.f, 0.f, 0.f};     // cell state (n=0 tile), regs enc->dec
  f32x4 cB = {0.f, 0.f, 0.f, 0.f};     // cell state (n=1 tile)

  for (int seg = 0; seg < 2; ++seg) {
    // ---- stage [32 cols x 2048 K] f16 weights into LDS ----
    const float* Wih; const float* Whh; int flip = 0;
    if (seg == 0) { Wih = layer ? eWih1 : eWih0; Whh = layer ? eWhh1 : eWhh0; }
    else { Wih = layer ? dWih1 : dWih0; Whh = layer ? dWhh1 : dWhh0; flip = (layer == 0); }
    const int k0 = tid * 8;
    for (int i = 0; i < 32; ++i) {
      int cc4 = i & 15, ct = i >> 4;
      int n = (cc4 >> 2) * 1024 + jb * 8 + ct * 4 + (cc4 & 3);
      half8 t;
      if (k0 < 1024) {
        if (flip) {
          #pragma unroll
          for (int e = 0; e < 8; ++e) t[e] = (_Float16)Wih[(size_t)n * 1024 + 1023 - k0 - e];
        } else {
          #pragma unroll
          for (int e = 0; e < 8; ++e) t[e] = (_Float16)Wih[(size_t)n * 1024 + k0 + e];
        }
      } else {
        #pragma unroll
        for (int e = 0; e < 8; ++e) t[e] = (_Float16)Whh[(size_t)n * 1024 + k0 - 1024 + e];
      }
      *(half8*)(lds + ((size_t)tid * 32 + i) * 8) = t;
    }
    const float* bi = (seg == 0) ? (layer ? ebi1 : ebi0) : (layer ? dbi1 : dbi0);
    const float* bh = (seg == 0) ? (layer ? ebh1 : ebh0) : (layer ? dbh1 : dbh0);
    const int nl0 = gi * 1024 + jb * 8 + (lane & 3);
    const float bb0 = bi[nl0] + bh[nl0];
    const float bb1 = bi[nl0 + 4] + bh[nl0 + 4];
    __syncthreads();
    DRAIN();  // clean vmcnt before counted phases

    const __half* ldsb = lds + ((size_t)kq * 32 + c4) * 8;
    __half* h0b = seg ? hD0 : hE0;

    half8 A0,A1,A2,A3,A4,A5,A6,A7, B0,B1,B2,B3,B4,B5,B6,B7,
          C0,C1,C2,C3,C4,C5,C6,C7, D0,D1,D2,D3,D4,D5,D6,D7,
          E0,E1,E2,E3,E4,E5,E6,E7, F0,F1,F2,F3,F4,F5,F6,F7;
    int havepf = 0;

    for (int p = 0; p <= 256; ++p) {
      // ---- start-of-iter wait (decoupled targets) ----
      const unsigned T  = (unsigned)(seg * 257 + p) * 128u;
      const unsigned tA = T;                                          // set0 (l0)
      const unsigned tB = (layer == 1) ? T
                         : ((seg == 1 && p == 0) ? 257u * 128u : 0u); // set1 (l1/femb)
      if (tid == 0 && (tA | tB)) {
        unsigned sA, sB;
        int g = 0;
        for (;;) {
          poll16(ctr, sA, sB);
          if (sA >= tA && sB >= tB) break;
          __builtin_amdgcn_s_sleep(1);
          if (++g > (1 << 18)) break;   // hang safety: break (wrong results, no hang)
        }
      }
      __syncthreads();

      const int active = (layer == 0) ? (p <= 255) : (p >= 1);
      if (active) {
        const __half* l0rec = (seg && p == 0) ? hE0 + (size_t)256 * HS
                                              : h0b + (size_t)p * HS;
        const __half* l1in  = h0b + (size_t)p * HS;
        const __half* l1rec = h1pp + (size_t)((p + 1) & 1) * HS;
        const __half* s1 = (layer == 0) ? l0rec : l1rec;
        const __half* s0;
        long long st0;
        if (layer == 0) {
          if (seg == 0)      { s0 = xf16 + (size_t)p * 1024;       st0 = 262144; }
          else if (p == 0)   { s0 = femb;                          st0 = 1024;   }
          else               { s0 = xf16 + (size_t)(p - 1) * 1024; st0 = 262144; }
        } else             { s0 = l1in;                            st0 = 1024;   }

        const __half* pa = s0 + (long long)arow * st0 + kq * 8;
        const __half* pb = s1 + (long long)arow * 1024 + kq * 8;
        f32x4 accA = {0.f, 0.f, 0.f, 0.f};
        f32x4 accB = {0.f, 0.f, 0.f, 0.f};
        if (havepf) PIPE_PF(); else PIPE_GENERIC();

        __half* hdst = (layer == 0) ? h0b + (size_t)(p + 1) * HS
                                    : h1pp + (size_t)(p & 1) * HS;
        EPI(accA, cA, bb0, 0);
        EPI(accB, cB, bb1, 1);
      }

      // ---- l0 x-prefetch for next iter (static read-only data: always safe) ----
      havepf = 0;
      if (layer == 0 && p < 255) {   // next iter p+1 <= 255 active, s0 is xf16
        const __half* ns0 = (seg == 0) ? xf16 + (size_t)(p + 1) * 1024
                                       : xf16 + (size_t)p * 1024;  // dec: s0(p+1)=x[p]
        const __half* npa = ns0 + (long long)arow * 262144 + kq * 8;
        PREFETCH_EF(npa);
        havepf = 1;
      }

      // ---- end-of-iter: drain stores+prefetch, arrive on own set ----
      DRAIN();
      __syncthreads();
      if (tid == 0)
        __hip_atomic_fetch_add(myarr, 1u, __ATOMIC_RELAXED, __HIP_MEMORY_SCOPE_AGENT);
    }
    __syncthreads();   // quiesce before next seg's LDS restage
  }
}

extern "C" void kernel_launch(void* const* d_in, const int* in_sizes, int n_in,
                              void* d_out, int out_size, void* d_ws, size_t ws_size,
                              hipStream_t stream) {
  const float* x     = (const float*)d_in[0];
  const float* eWih0 = (const float*)d_in[1];
  const float* eWhh0 = (const float*)d_in[2];
  const float* ebih0 = (const float*)d_in[3];
  const float* ebhh0 = (const float*)d_in[4];
  const float* eWih1 = (const float*)d_in[5];
  const float* eWhh1 = (const float*)d_in[6];
  const float* ebih1 = (const float*)d_in[7];
  const float* ebhh1 = (const float*)d_in[8];
  const float* dWih0 = (const float*)d_in[9];
  const float* dWhh0 = (const float*)d_in[10];
  const float* dbih0 = (const float*)d_in[11];
  const float* dbhh0 = (const float*)d_in[12];
  const float* dWih1 = (const float*)d_in[13];
  const float* dWhh1 = (const float*)d_in[14];
  const float* dbih1 = (const float*)d_in[15];
  const float* dbhh1 = (const float*)d_in[16];
  float* out = (float*)d_out;

  char* ws = (char*)d_ws;
  size_t off = 0;
  auto alloc = [&](size_t bytes) { char* p = ws + off; off += (bytes + 255) & ~(size_t)255; return p; };
  const size_t SLOT = (size_t)HS * sizeof(__half);            // 128KB
  __half* xf16 = (__half*)alloc((size_t)64 * 256 * 1024 * sizeof(__half));  // 32MB
  __half* hE0  = (__half*)alloc(257 * SLOT);                  // 32.1MB fresh slots
  __half* hD0  = (__half*)alloc(257 * SLOT);                  // 32.1MB fresh slots
  __half* h1pp = (__half*)alloc(2 * SLOT);                    // h1 ping-pong (coherent)
  __half* femb = (__half*)alloc(SLOT);
  unsigned* ctr = (unsigned*)alloc(8192);

  if (ws_size < off) {  // loud failure: absmax == ws_size in MB * 1e6
    hipLaunchKernelGGL(fail_mark, dim3(1), dim3(1), 0, stream,
                       out, (float)(ws_size >> 20));
    return;
  }

  const int xn = 64 * 256 * 1024;
  cvt_x<<<(xn + 255) / 256, 256, 0, stream>>>(x, xf16, xn);

  hipMemsetAsync(hE0, 0, SLOT, stream);   // h0 slot0 = zeros
  hipMemsetAsync(h1pp, 0, SLOT, stream);  // h1 slot0 = zeros
  hipMemsetAsync(ctr, 0, 8192, stream);

  hipFuncSetAttribute((const void*)lstm_persist,
                      hipFuncAttributeMaxDynamicSharedMemorySize, LDS_BYTES);
  lstm_persist<<<NBLK, NTHR, LDS_BYTES, stream>>>(
      xf16,
      eWih0, eWhh0, eWih1, eWhh1, dWih0, dWhh0, dWih1, dWhh1,
      ebih0, ebhh0, ebih1, ebhh1, dbih0, dbhh0, dbih1, dbhh1,
      hE0, hD0, h1pp, femb, out, ctr);
}